// Round 12
// baseline (92.549 us; speedup 1.0000x reference)
//
#include <hip/hip_runtime.h>

#define BATCH 16
#define HH 512
#define WW 512
#define PLANE (HH*WW)

// Compiler memory-order fences for wave-synchronous LDS exchange (used by K2).
#define LDS_WAIT()   asm volatile("s_waitcnt lgkmcnt(0)" ::: "memory")
#define WAVE_FENCE() asm volatile("" ::: "memory")

// bf16 pair helpers: word = x in low 16 bits, y in high 16 bits
__device__ __forceinline__ float bf_lo(unsigned u) {
    union { unsigned u; float f; } c; c.u = u << 16; return c.f;
}
__device__ __forceinline__ float bf_hi(unsigned u) {
    union { unsigned u; float f; } c; c.u = u & 0xFFFF0000u; return c.f;
}
__device__ __forceinline__ unsigned f2bf(float f) {   // RTNE, returns low-16 bf16
    union { float f; unsigned u; } c; c.f = f;
    return (c.u + 0x7FFFu + ((c.u >> 16) & 1u)) >> 16;
}
__device__ __forceinline__ unsigned packbf(float x, float y) {
    return f2bf(x) | (f2bf(y) << 16);
}
__device__ __forceinline__ float min3f(float a, float b, float c) {
    return fminf(fminf(a, b), c);    // clang fuses to v_min3_f32
}

// ---------------- K1: guide (channel mean) + 15x15 replicate min-pool -> packed bf16 (g,p) ----------------
#define T1 64
#define HALO 7
#define LW (T1 + 2*HALO)   // 78

__global__ __launch_bounds__(256) void k1_guide_minpool(
    const float* __restrict__ smoky, unsigned* __restrict__ gp)
{
    __shared__ float dcp[LW*LW];          // per-pixel channel min, with replicate halo
    __shared__ float vmn[T1*LW];          // vertical 15-min
    __shared__ unsigned short gsh[T1*T1]; // guide (bf16) for interior
    int nwg = gridDim.x;             // 1024, divisible by 8
    int wg = (blockIdx.x & 7) * (nwg >> 3) + (blockIdx.x >> 3);  // XCD-chunked swizzle
    int img  = wg >> 6;              // 64 tiles per image
    int tile = wg & 63;
    int y0 = (tile >> 3) * T1;
    int x0 = (tile & 7) * T1;
    int t = threadIdx.x;
    const float* s0 = smoky + (size_t)img * 3 * PLANE;
    unsigned* gpl = gp + (size_t)img * PLANE;

    for (int i = t; i < LW*LW; i += 256) {
        int ly = i / LW, lx = i - ly * LW;
        int iy = y0 - HALO + ly, ix = x0 - HALO + lx;
        int cy = min(max(iy, 0), HH-1);
        int cx = min(max(ix, 0), WW-1);
        const float* bp = s0 + cy * WW + cx;
        float c0 = bp[0], c1 = bp[PLANE], c2 = bp[2*PLANE];
        dcp[i] = min3f(c0, c1, c2);
        if (ly >= HALO && ly < HALO+T1 && lx >= HALO && lx < HALO+T1)
            gsh[(ly-HALO)*T1 + (lx-HALO)] = (unsigned short)f2bf((c0 + c1 + c2) * (1.0f/3.0f));
    }
    __syncthreads();
    for (int i = t; i < T1*LW; i += 256) {
        int r = i / LW, c = i - r * LW;
        const float* q = &dcp[r*LW + c];
        float m = min3f(min3f(min3f(q[0*LW],q[1*LW],q[2*LW]),
                              min3f(q[3*LW],q[4*LW],q[5*LW]),
                              min3f(q[6*LW],q[7*LW],q[8*LW])),
                        min3f(q[9*LW],q[10*LW],q[11*LW]),
                        min3f(q[12*LW],q[13*LW],q[14*LW]));
        vmn[i] = m;
    }
    __syncthreads();
    for (int i = t; i < T1*T1; i += 256) {
        int r = i >> 6, c = i & 63;
        const float* q = &vmn[r*LW + c];
        float m = min3f(min3f(min3f(q[0],q[1],q[2]),
                              min3f(q[3],q[4],q[5]),
                              min3f(q[6],q[7],q[8])),
                        min3f(q[9],q[10],q[11]),
                        min3f(q[12],q[13],q[14]));
        gpl[(y0+r)*WW + x0 + c] = (unsigned)gsh[r*T1+c] | (f2bf(m) << 16);
    }
}

// ================= K2: vectorized sliding stage (unchanged from R11) =================
#define RS2 8

__global__ __launch_bounds__(256) void k2_ab(
    const unsigned* __restrict__ gp, unsigned* __restrict__ abO)
{
    __shared__ float2 eo[4][4][80];   // [wave][quantity][slot]
    int nwg = gridDim.x;             // 1024
    int wg = (blockIdx.x & 7) * (nwg >> 3) + (blockIdx.x >> 3);
    int w = threadIdx.x >> 6, l = threadIdx.x & 63;
    int gw = wg * 4 + w;             // 0..4095
    int img   = gw >> 8;             // 256 waves per image
    int cg    = (gw >> 6) & 3;       // 4 column groups of 128
    int strip = gw & 63;             // 64 row-strips of 8
    int y0 = strip * RS2;
    int c0 = cg * 128;
    const unsigned* gpP = gp + (size_t)img * PLANE;
    unsigned* abP = abO + (size_t)img * PLANE;

    int cm = c0 + 2*l;               // main cols cm, cm+1 (always in [0,511])
    int hj = l & 3;
    int hcol  = (l < 4) ? (c0 - 8 + 2*hj) : (c0 + 128 + 2*hj);
    bool hv   = (l < 8) && (hcol >= 0) && (hcol < WW);
    int hslot = (l < 4) ? hj : (68 + hj);

    float sI[2]={0,0}, sII[2]={0,0}, sPv[2]={0,0}, sIp[2]={0,0};
    float hI[2]={0,0}, hII[2]={0,0}, hPv[2]={0,0}, hIp[2]={0,0};

    auto loadrow = [&](int y, uint2& um, uint2& uh) {
        int yc = min(max(y, 0), HH-1);
        const unsigned* r = gpP + (size_t)yc * WW;
        uint2 a = *reinterpret_cast<const uint2*>(r + cm);
        uint2 b = make_uint2(0u, 0u);
        if (hv) b = *reinterpret_cast<const uint2*>(r + hcol);
        bool rv = ((unsigned)y < (unsigned)HH);
        um.x = rv ? a.x : 0u;  um.y = rv ? a.y : 0u;
        uh.x = rv ? b.x : 0u;  uh.y = rv ? b.y : 0u;
    };

    for (int r = y0 - 8; r <= y0 + 6; ++r) {
        uint2 um, uh; loadrow(r, um, uh);
        unsigned mm[2]={um.x,um.y}, hh[2]={uh.x,uh.y};
        #pragma unroll
        for (int k = 0; k < 2; ++k) {
            float g=bf_lo(mm[k]), p=bf_hi(mm[k]);
            sI[k]+=g; sII[k]+=g*g; sPv[k]+=p; sIp[k]+=g*p;
            float gh=bf_lo(hh[k]), ph=bf_hi(hh[k]);
            hI[k]+=gh; hII[k]+=gh*gh; hPv[k]+=ph; hIp[k]+=gh*ph;
        }
    }
    uint2 adM, adH, sbM, sbH;
    loadrow(y0 + 7, adM, adH);
    loadrow(y0 - 8, sbM, sbH);

    float2* EO = &eo[w][0][0];
    const float inv225 = 1.0f/225.0f;
    for (int y = y0; y < y0 + RS2; ++y) {
        {
            unsigned am[2]={adM.x,adM.y}, sm[2]={sbM.x,sbM.y};
            unsigned ah[2]={adH.x,adH.y}, sh[2]={sbH.x,sbH.y};
            #pragma unroll
            for (int k = 0; k < 2; ++k) {
                float gA=bf_lo(am[k]), pA=bf_hi(am[k]);
                float gS=bf_lo(sm[k]), pS=bf_hi(sm[k]);
                sI[k]+=gA-gS; sII[k]+=gA*gA-gS*gS; sPv[k]+=pA-pS; sIp[k]+=gA*pA-gS*pS;
                float gAh=bf_lo(ah[k]), pAh=bf_hi(ah[k]);
                float gSh=bf_lo(sh[k]), pSh=bf_hi(sh[k]);
                hI[k]+=gAh-gSh; hII[k]+=gAh*gAh-gSh*gSh; hPv[k]+=pAh-pSh; hIp[k]+=gAh*pAh-gSh*pSh;
            }
        }
        loadrow(y + 8, adM, adH);
        loadrow(y - 7, sbM, sbH);
        EO[l+4]       = make_float2(sI[0],  sI[1]);
        EO[80 + l+4]  = make_float2(sII[0], sII[1]);
        EO[160 + l+4] = make_float2(sPv[0], sPv[1]);
        EO[240 + l+4] = make_float2(sIp[0], sIp[1]);
        if (l < 8) {
            EO[hslot]       = make_float2(hI[0],  hI[1]);
            EO[80 + hslot]  = make_float2(hII[0], hII[1]);
            EO[160 + hslot] = make_float2(hPv[0], hPv[1]);
            EO[240 + hslot] = make_float2(hIp[0], hIp[1]);
        }
        LDS_WAIT();
        float S0[4], S1[4];
        #pragma unroll
        for (int q = 0; q < 4; ++q) {
            float2 t[9];
            #pragma unroll
            for (int m = 0; m < 9; ++m) t[m] = EO[q*80 + l + m];
            float so = ((t[0].y+t[1].y)+(t[2].y+t[3].y)) + ((t[4].y+t[5].y)+(t[6].y+t[7].y));
            float se = ((t[1].x+t[2].x)+(t[3].x+t[4].x)) + ((t[5].x+t[6].x)+t[7].x);
            S0[q] = so + se;
            S1[q] = S0[q] - t[0].y + t[8].x;
        }
        WAVE_FENCE();
        unsigned pk0, pk1;
        {
            float mI = S0[0]*inv225, mP = S0[2]*inv225;
            float va = (S0[3]*inv225 - mI*mP) / (S0[1]*inv225 - mI*mI + 1e-3f);
            pk0 = packbf(va, mP - va*mI);
        }
        {
            float mI = S1[0]*inv225, mP = S1[2]*inv225;
            float va = (S1[3]*inv225 - mI*mP) / (S1[1]*inv225 - mI*mI + 1e-3f);
            pk1 = packbf(va, mP - va*mI);
        }
        *reinterpret_cast<uint2*>(abP + (size_t)y*WW + cm) = make_uint2(pk0, pk1);
    }
}

// ================= K3: barrier-tile box filter of (a,b) + guided output + combine =================
// 64x64 output tile per block. Phases: stage ab halo -> vertical sums -> horizontal
// sums (means) -> streaming emit. All loads of a phase issue before any wait.
#define T3 64
#define AW 78           // tile + 2*7
#define VSW 82          // padded vs row width: stride 656B -> bank shift 4/row

__global__ __launch_bounds__(256) void k3_final(
    const unsigned* __restrict__ abI,
    const float* __restrict__ smoky, const float* __restrict__ rho,
    float* __restrict__ out)
{
    __shared__ unsigned abt[AW*AW];      // 78*78*4 = 24.3 KB; reused as m[64*64] in phase H/E
    __shared__ float2 vs[T3*VSW];        // 64*82*8 = 42.0 KB
    int nwg = gridDim.x;                 // 1024
    int wg = (blockIdx.x & 7) * (nwg >> 3) + (blockIdx.x >> 3);
    int img  = wg >> 6;                  // 64 tiles per image
    int tile = wg & 63;
    int y0 = (tile >> 3) * T3;
    int x0 = (tile & 7) * T3;
    int t = threadIdx.x;
    const unsigned* abP = abI + (size_t)img * PLANE;
    const float* sP = smoky + (size_t)img * 3 * PLANE;
    const float* rP = rho   + (size_t)img * 3 * PLANE;
    float* oP = out + (size_t)img * 3 * PLANE;

    // ---- Phase 0: stage ab halo tile (zero-pad outside image) ----
    for (int i = t; i < AW*AW; i += 256) {
        int ly = i / AW, lx = i - ly * AW;
        int gy = y0 - 7 + ly, gx = x0 - 7 + lx;
        unsigned v = 0u;
        if ((unsigned)gy < (unsigned)HH && (unsigned)gx < (unsigned)WW)
            v = abP[(size_t)gy * WW + gx];
        abt[i] = v;
    }
    __syncthreads();

    // ---- Phase V: vertical 15-tap sliding sums -> vs[r][c], r=0..63, c=0..77 ----
    if (t < 234) {
        int rb = (t >= 156) ? 2 : (t >= 78 ? 1 : 0);
        int c  = t - rb * 78;
        int r0 = (rb == 0) ? 0 : (rb == 1 ? 22 : 43);
        int r1 = (rb == 0) ? 21 : (rb == 1 ? 42 : 63);
        float sA = 0.f, sB = 0.f;
        #pragma unroll
        for (int k = 0; k < 15; ++k) {
            unsigned u = abt[(r0 + k)*AW + c];
            sA += bf_lo(u); sB += bf_hi(u);
        }
        vs[r0*VSW + c] = make_float2(sA, sB);
        for (int r = r0 + 1; r <= r1; ++r) {
            unsigned ua = abt[(r + 14)*AW + c];
            unsigned us = abt[(r - 1)*AW + c];
            sA += bf_lo(ua) - bf_lo(us);
            sB += bf_hi(ua) - bf_hi(us);
            vs[r*VSW + c] = make_float2(sA, sB);
        }
    }
    __syncthreads();

    // ---- Phase H: horizontal 15-tap sliding sums -> means packed bf16 in m (aliases abt) ----
    unsigned* m = abt;
    {
        int r = t >> 2, g = t & 3;
        const float2* vr = &vs[r*VSW + g*16];
        const float inv225 = 1.0f/225.0f;
        float SA, SB;
        {
            float2 a0=vr[0], a1=vr[1], a2=vr[2], a3=vr[3], a4=vr[4], a5=vr[5], a6=vr[6], a7=vr[7];
            float2 a8=vr[8], a9=vr[9], a10=vr[10], a11=vr[11], a12=vr[12], a13=vr[13], a14=vr[14];
            SA = (((a0.x+a1.x)+(a2.x+a3.x)) + ((a4.x+a5.x)+(a6.x+a7.x)))
               + (((a8.x+a9.x)+(a10.x+a11.x)) + ((a12.x+a13.x)+a14.x));
            SB = (((a0.y+a1.y)+(a2.y+a3.y)) + ((a4.y+a5.y)+(a6.y+a7.y)))
               + (((a8.y+a9.y)+(a10.y+a11.y)) + ((a12.y+a13.y)+a14.y));
        }
        m[r*64 + g*16] = packbf(SA*inv225, SB*inv225);
        #pragma unroll
        for (int j = 1; j < 16; ++j) {
            float2 ua = vr[14 + j];
            float2 us = vr[j - 1];
            SA += ua.x - us.x;
            SB += ua.y - us.y;
            m[r*64 + g*16 + j] = packbf(SA*inv225, SB*inv225);
        }
    }
    __syncthreads();

    // ---- Phase E: streaming emit (float2 lanes; guide recomputed in-register) ----
    const float inv11 = 1.0f/1.1f;
    const float third = 1.0f/3.0f;
    #pragma unroll
    for (int it = 0; it < 8; ++it) {
        int i2 = it*256 + t;            // pair index 0..2047
        int r  = i2 >> 5;               // 32 pairs per row
        int cp = (i2 & 31) * 2;
        size_t off = (size_t)(y0 + r)*WW + x0 + cp;
        float2 s0 = *reinterpret_cast<const float2*>(sP + off);
        float2 s1 = *reinterpret_cast<const float2*>(sP + off + PLANE);
        float2 s2 = *reinterpret_cast<const float2*>(sP + off + 2*PLANE);
        float2 r0 = *reinterpret_cast<const float2*>(rP + off);
        float2 r1 = *reinterpret_cast<const float2*>(rP + off + PLANE);
        float2 r2 = *reinterpret_cast<const float2*>(rP + off + 2*PLANE);
        unsigned m0 = m[r*64 + cp], m1 = m[r*64 + cp + 1];
        float g0 = (s0.x + s1.x + s2.x) * third;
        float g1 = (s0.y + s1.y + s2.y) * third;
        float q0 = (0.1f + bf_lo(m0)*g0 + bf_hi(m0)) * inv11;
        float q1 = (0.1f + bf_lo(m1)*g1 + bf_hi(m1)) * inv11;
        float2 o0, o1, o2;
        o0.x = s0.x - q0*(1.0f - r0.x);  o0.y = s0.y - q1*(1.0f - r0.y);
        o1.x = s1.x - q0*(1.0f - r1.x);  o1.y = s1.y - q1*(1.0f - r1.y);
        o2.x = s2.x - q0*(1.0f - r2.x);  o2.y = s2.y - q1*(1.0f - r2.y);
        *reinterpret_cast<float2*>(oP + off)           = o0;
        *reinterpret_cast<float2*>(oP + off + PLANE)   = o1;
        *reinterpret_cast<float2*>(oP + off + 2*PLANE) = o2;
    }
}

extern "C" void kernel_launch(void* const* d_in, const int* in_sizes, int n_in,
                              void* d_out, int out_size, void* d_ws, size_t ws_size,
                              hipStream_t stream) {
    const float* smoky = (const float*)d_in[0];
    const float* rho   = (const float*)d_in[1];
    float* out = (float*)d_out;
    const size_t P = (size_t)BATCH * PLANE;
    unsigned* gpbuf = (unsigned*)d_ws;        // packed bf16 (guide,p): P u32
    unsigned* abbuf = (unsigned*)d_ws + P;    // packed bf16 (a,b): P u32

    k1_guide_minpool<<<BATCH*64, 256, 0, stream>>>(smoky, gpbuf);
    k2_ab<<<BATCH*64, 256, 0, stream>>>(gpbuf, abbuf);
    k3_final<<<BATCH*64, 256, 0, stream>>>(abbuf, smoky, rho, out);
}